// Round 8
// baseline (185.990 us; speedup 1.0000x reference)
//
#include <hip/hip_runtime.h>
#include <cstddef>

#define NB   16
#define CIN  512
#define NTOK 1600   // 40*40
#define HCH  64
#define LDA  72     // padded LDS row stride (bf16 elems), mult of 8 for 16B loads

typedef __attribute__((ext_vector_type(8))) short bf16x8;
typedef __attribute__((ext_vector_type(4))) float f32x4;

__device__ __forceinline__ unsigned short f2bf(float x) {
    union { float f; unsigned u; } v; v.f = x;
    unsigned r = v.u + 0x7FFFu + ((v.u >> 16) & 1u);   // round-nearest-even
    return (unsigned short)(r >> 16);
}

__device__ __forceinline__ unsigned cvtpk_bf16(float lo, float hi) {
    unsigned r;
    asm("v_cvt_pk_bf16_f32 %0, %1, %2" : "=v"(r) : "v"(lo), "v"(hi));
    return r;
}

__device__ __forceinline__ float fast_exp2(float x) {
#if __has_builtin(__builtin_amdgcn_exp2f)
    return __builtin_amdgcn_exp2f(x);
#else
    return exp2f(x);
#endif
}

// ---------------------------------------------------------------------------
// Weight prep: Wt[3][64h][512c] = {wq,wk,wv}^T ; WoT[512c][64j] = wo^T
// ---------------------------------------------------------------------------
__global__ void __launch_bounds__(256) wprep_kernel(
    const float* __restrict__ wq, const float* __restrict__ wk,
    const float* __restrict__ wv, const float* __restrict__ wo,
    unsigned short* __restrict__ Wt, unsigned short* __restrict__ WoT)
{
    const int gid = blockIdx.x * 256 + threadIdx.x;
    if (gid < 3 * HCH * (CIN / 8)) {               // 12288 Wt threads
        const int h  = gid & 63;
        const int c8 = (gid >> 6) & 63;
        const int t  = gid >> 12;
        const float* w = (t == 0) ? wq : (t == 1) ? wk : wv;
        ushort4 lo, hi;
        lo.x = f2bf(w[(size_t)(c8 * 8 + 0) * HCH + h]);
        lo.y = f2bf(w[(size_t)(c8 * 8 + 1) * HCH + h]);
        lo.z = f2bf(w[(size_t)(c8 * 8 + 2) * HCH + h]);
        lo.w = f2bf(w[(size_t)(c8 * 8 + 3) * HCH + h]);
        hi.x = f2bf(w[(size_t)(c8 * 8 + 4) * HCH + h]);
        hi.y = f2bf(w[(size_t)(c8 * 8 + 5) * HCH + h]);
        hi.z = f2bf(w[(size_t)(c8 * 8 + 6) * HCH + h]);
        hi.w = f2bf(w[(size_t)(c8 * 8 + 7) * HCH + h]);
        ushort4* dst = (ushort4*)(Wt + ((size_t)t * HCH + h) * CIN + c8 * 8);
        dst[0] = lo; dst[1] = hi;
    } else {                                        // 4096 WoT threads
        const int g  = gid - 3 * HCH * (CIN / 8);
        const int c  = g & 511;
        const int j8 = g >> 9;
        ushort4 lo, hi;
        lo.x = f2bf(wo[(size_t)(j8 * 8 + 0) * CIN + c]);
        lo.y = f2bf(wo[(size_t)(j8 * 8 + 1) * CIN + c]);
        lo.z = f2bf(wo[(size_t)(j8 * 8 + 2) * CIN + c]);
        lo.w = f2bf(wo[(size_t)(j8 * 8 + 3) * CIN + c]);
        hi.x = f2bf(wo[(size_t)(j8 * 8 + 4) * CIN + c]);
        hi.y = f2bf(wo[(size_t)(j8 * 8 + 5) * CIN + c]);
        hi.z = f2bf(wo[(size_t)(j8 * 8 + 6) * CIN + c]);
        hi.w = f2bf(wo[(size_t)(j8 * 8 + 7) * CIN + c]);
        ushort4* dst = (ushort4*)(WoT + (size_t)c * HCH + j8 * 8);
        dst[0] = lo; dst[1] = hi;
    }
}

// ---------------------------------------------------------------------------
// Projection pipeline pieces.
// Input tile: f32 -> bf16 transpose to As (padded LDA, chunk-XOR swizzle)
// via register carry (issue-early / write-late, T14). Weight tile: bf16,
// staged via global_load_lds into unpadded [row][128B] LDS with XOR swizzle
// byte ^= (row&7)<<4 applied on the SOURCE address (dest linear) and on the
// fragment read (involution) -- identical discipline to the attn kernel.
// ---------------------------------------------------------------------------
__device__ __forceinline__ void proj_load_in(
    const float* __restrict__ gsb, int c0, int nq, float4 (&inr)[4])
{
    #pragma unroll
    for (int rep = 0; rep < 4; ++rep)
        inr[rep] = ((const float4*)(gsb + (size_t)c0 * NTOK))[rep * 4 + nq];
}

__device__ __forceinline__ void proj_write_as(
    unsigned short* Ab, const float4 (&inr)[4], int nq, int swz, int clo)
{
    #pragma unroll
    for (int rep = 0; rep < 4; ++rep) {
        const int nn4 = rep * 4 + nq;
        const float4 a = inr[rep];
        const int n = nn4 * 4;
        const int i01 = ((swz ^ ((n >> 1) & 6)) << 3) + clo;
        const int i23 = ((swz ^ (((n + 2) >> 1) & 6)) << 3) + clo;
        Ab[(n + 0) * LDA + i01] = f2bf(a.x);
        Ab[(n + 1) * LDA + i01] = f2bf(a.y);
        Ab[(n + 2) * LDA + i23] = f2bf(a.z);
        Ab[(n + 3) * LDA + i23] = f2bf(a.w);
    }
}

template<int NW>
__device__ __forceinline__ void proj_dma_w(
    const unsigned short* __restrict__ wbase, int c0,
    unsigned short* Wb, int wv_, int lane)
{
    const int sr = lane >> 3;                 // row within 8-row chunk
    const int sc = 8 * ((lane & 7) ^ sr);     // inverse-swizzled source col
    #pragma unroll
    for (int r = 0; r < 2 * NW; ++r) {
        const int row0 = r * 32 + wv_ * 8;
        __builtin_amdgcn_global_load_lds(
            wbase + (size_t)(row0 + sr) * CIN + c0 + sc,
            (char*)Wb + row0 * 128, 16, 0, 0);
    }
}

template<int NW>
__device__ __forceinline__ void proj_compute(
    const unsigned short* Ab, const unsigned short* Wb,
    int wv_, int l16, int quad, int swzr, f32x4 (&acc)[NW][4])
{
    #pragma unroll
    for (int k0 = 0; k0 < 2; ++k0) {
        const bf16x8 av = *((const bf16x8*)(Ab + (wv_ * 16 + l16) * LDA + ((k0 * 4 + quad) ^ swzr) * 8));
        const int colb = (k0 * 64 + quad * 16) ^ ((l16 & 7) << 4);
        #pragma unroll
        for (int t = 0; t < NW; ++t)
            #pragma unroll
            for (int nt = 0; nt < 4; ++nt) {
                const bf16x8 bv = *((const bf16x8*)((const char*)Wb + (t * 64 + nt * 16 + l16) * 128 + colb));
                acc[t][nt] = __builtin_amdgcn_mfma_f32_16x16x32_bf16(av, bv, acc[t][nt], 0, 0, 0);
            }
    }
}

// Counted-vmcnt double-buffered pipeline: weights prefetched via DMA (no
// VGPRs -> compiler cannot serialize), inputs prefetched via 16-VGPR carry.
template<int NW>
__device__ __forceinline__ void proj_body(
    const float* __restrict__ src, const unsigned short* __restrict__ wbase,
    unsigned short* __restrict__ Q, unsigned short* __restrict__ K,
    unsigned short* __restrict__ Vt,
    unsigned short* As, unsigned short* Wl, int b, int n0, int tid)
{
    const int wv_  = tid >> 6;
    const int lane = tid & 63;
    const int l16  = lane & 15, quad = lane >> 4;
    const int cc   = tid >> 2, nq = tid & 3;
    const int swz  = cc >> 3,  clo = cc & 7;
    const int swzr = (l16 >> 1) & 6;

    f32x4 acc[NW][4];
    #pragma unroll
    for (int t = 0; t < NW; ++t)
        #pragma unroll
        for (int nt = 0; nt < 4; ++nt)
            #pragma unroll
            for (int r = 0; r < 4; ++r) acc[t][nt][r] = 0.f;

    const float* gsb = src + ((size_t)b * CIN + cc) * NTOK + n0;

    float4 inr[4];
    // ---- prologue: tile0 + tile1 in flight ----
    proj_load_in(gsb, 0, nq, inr);
    __builtin_amdgcn_sched_barrier(0);
    proj_dma_w<NW>(wbase, 0, Wl, wv_, lane);
    if constexpr (NW == 2) asm volatile("s_waitcnt vmcnt(4)" ::: "memory");
    else                   asm volatile("s_waitcnt vmcnt(2)" ::: "memory");
    __builtin_amdgcn_sched_barrier(0);
    proj_write_as(As, inr, nq, swz, clo);
    proj_load_in(gsb, 64, nq, inr);
    __builtin_amdgcn_sched_barrier(0);
    proj_dma_w<NW>(wbase, 64, Wl + 128 * 64, wv_, lane);
    if constexpr (NW == 2) asm volatile("s_waitcnt vmcnt(8) lgkmcnt(0)" ::: "memory");
    else                   asm volatile("s_waitcnt vmcnt(6) lgkmcnt(0)" ::: "memory");
    __builtin_amdgcn_sched_barrier(0);
    __builtin_amdgcn_s_barrier();
    __builtin_amdgcn_sched_barrier(0);

    for (int t = 0; t < 8; ++t) {
        proj_compute<NW>(As + (t & 1) * (64 * LDA), Wl + (t & 1) * (128 * 64),
                         wv_, l16, quad, swzr, acc);
        __builtin_amdgcn_sched_barrier(0);
        __builtin_amdgcn_s_barrier();
        __builtin_amdgcn_sched_barrier(0);
        if (t < 7) {
            // retire tile t+1 input loads (weight DMAs of t+1 stay in flight)
            if constexpr (NW == 2) asm volatile("s_waitcnt vmcnt(4)" ::: "memory");
            else                   asm volatile("s_waitcnt vmcnt(2)" ::: "memory");
            __builtin_amdgcn_sched_barrier(0);
            proj_write_as(As + ((t + 1) & 1) * (64 * LDA), inr, nq, swz, clo);
            if (t < 6) {
                proj_load_in(gsb, (t + 2) * 64, nq, inr);
                __builtin_amdgcn_sched_barrier(0);
                proj_dma_w<NW>(wbase, (t + 2) * 64, Wl + (t & 1) * (128 * 64), wv_, lane);
                if constexpr (NW == 2) asm volatile("s_waitcnt vmcnt(8) lgkmcnt(0)" ::: "memory");
                else                   asm volatile("s_waitcnt vmcnt(6) lgkmcnt(0)" ::: "memory");
            } else {
                asm volatile("s_waitcnt vmcnt(0) lgkmcnt(0)" ::: "memory");
            }
            __builtin_amdgcn_sched_barrier(0);
            __builtin_amdgcn_s_barrier();
            __builtin_amdgcn_sched_barrier(0);
        }
    }

    // ---- epilogues (verbatim from verified R3/R7 kernel) ----
    if constexpr (NW == 2) {
        const float qscale = 0.18033688f;          // 0.125 / ln(2)
        #pragma unroll
        for (int nt = 0; nt < 4; ++nt) {
            const int h = nt * 16 + l16;
            #pragma unroll
            for (int r = 0; r < 4; ++r) {
                const int n = n0 + wv_ * 16 + quad * 4 + r;
                Q[((size_t)b * NTOK + n) * HCH + h] = f2bf(acc[0][nt][r] * qscale);
                K[((size_t)b * NTOK + n) * HCH + h] = f2bf(acc[1][nt][r]);
            }
        }
    } else {
        // permuted V store: keys n0 + wv_*16 + quad*4 + (0..3)
        // go to positions n0 + (wv_&1)*32 + quad*8 + (wv_>>1)*4 + (0..3)
        const int pbase = n0 + (wv_ & 1) * 32 + quad * 8 + (wv_ >> 1) * 4;
        #pragma unroll
        for (int nt = 0; nt < 4; ++nt) {
            const int h = nt * 16 + l16;
            ushort4 pv;
            pv.x = f2bf(acc[0][nt][0]); pv.y = f2bf(acc[0][nt][1]);
            pv.z = f2bf(acc[0][nt][2]); pv.w = f2bf(acc[0][nt][3]);
            *((ushort4*)(Vt + ((size_t)b * HCH + h) * NTOK + pbase)) = pv;
        }
    }
}

__global__ void __launch_bounds__(256) proj_kernel(
    const float* __restrict__ rgb, const float* __restrict__ hsi,
    const unsigned short* __restrict__ Wt,
    unsigned short* __restrict__ Q, unsigned short* __restrict__ K,
    unsigned short* __restrict__ Vt)
{
    __shared__ __align__(16) unsigned short As[2 * 64 * LDA];    // 18432 B
    __shared__ __align__(16) unsigned short Wl[2 * 128 * 64];    // 32768 B

    const int which = blockIdx.y;                 // 0: QK, 1: V
    const int b     = blockIdx.x / 25;
    const int n0    = (blockIdx.x % 25) * 64;
    const unsigned short* wbase = Wt + (which ? (size_t)2 * HCH * CIN : 0);

    if (which == 0)
        proj_body<2>(rgb, wbase, Q, K, Vt, As, Wl, b, n0, threadIdx.x);
    else
        proj_body<1>(hsi, wbase, Q, K, Vt, As, Wl, b, n0, threadIdx.x);
}

// ---------------------------------------------------------------------------
// Attention: split-Q + LDS-staged K/V tiles via global_load_lds with a
// counted-vmcnt double buffer (verified R7).
// ---------------------------------------------------------------------------
__device__ __forceinline__ void attn_stage_tile(
    const unsigned short* __restrict__ Kg, const unsigned short* __restrict__ Vg,
    char* buf, int kt, int wv_, int srow, int scole)
{
    #pragma unroll
    for (int i = 0; i < 2; ++i) {
        const int ck  = i * 4 + wv_;          // chunk 0..7 across waves
        const int row = ck * 8 + srow;        // K: key row / V: h row, 0..63
        const unsigned short* ksrc = Kg + (size_t)(kt * 64 + row) * HCH + scole;
        __builtin_amdgcn_global_load_lds(ksrc, buf + ck * 1024, 16, 0, 0);
        const unsigned short* vsrc = Vg + (size_t)row * NTOK + kt * 64 + scole;
        __builtin_amdgcn_global_load_lds(vsrc, buf + 8192 + ck * 1024, 16, 0, 0);
    }
}

__device__ __forceinline__ void attn_compute_lds(
    const char* kbuf, const char* vbuf, int l16, int quad,
    const bf16x8 (&qa)[2], f32x4 (&o)[4], float& rs)
{
    // ---- fragment reads (swizzled): logical col bytes k0*64+quad*16 ----
    bf16x8 kb[2][4], vb[2][4];
    #pragma unroll
    for (int k0 = 0; k0 < 2; ++k0) {
        const int colb = (k0 * 64 + quad * 16) ^ ((l16 & 7) << 4);
        #pragma unroll
        for (int nt = 0; nt < 4; ++nt) {
            kb[k0][nt] = *((const bf16x8*)(kbuf + (nt * 16 + l16) * 128 + colb));
            vb[k0][nt] = *((const bf16x8*)(vbuf + (nt * 16 + l16) * 128 + colb));
        }
    }

    // ---- S^T = K Q^T : col = q (l16), row = key (quad*4+r) ----
    f32x4 s[4];
    #pragma unroll
    for (int nt = 0; nt < 4; ++nt)
        #pragma unroll
        for (int r = 0; r < 4; ++r) s[nt][r] = 0.f;
    #pragma unroll
    for (int k0 = 0; k0 < 2; ++k0)
        #pragma unroll
        for (int nt = 0; nt < 4; ++nt)
            s[nt] = __builtin_amdgcn_mfma_f32_16x16x32_bf16(kb[k0][nt], qa[k0], s[nt], 0, 0, 0);

    // ---- P = exp2(S^T) in-lane, pack bf16 pairs, accumulate row sums ----
    unsigned dA[4], dB[4];
    #pragma unroll
    for (int nt = 0; nt < 4; ++nt) {
        const float e0 = fast_exp2(s[nt][0]);
        const float e1 = fast_exp2(s[nt][1]);
        const float e2 = fast_exp2(s[nt][2]);
        const float e3 = fast_exp2(s[nt][3]);
        rs += (e0 + e1) + (e2 + e3);
        dA[nt] = cvtpk_bf16(e0, e1);
        dB[nt] = cvtpk_bf16(e2, e3);
    }

    // ---- O += P V (V stored pre-permuted to match this packing) ----
    #pragma unroll
    for (int k0 = 0; k0 < 2; ++k0) {
        union { bf16x8 v; unsigned u[4]; } pu;
        pu.u[0] = dA[k0];
        pu.u[1] = dB[k0];
        pu.u[2] = dA[k0 + 2];
        pu.u[3] = dB[k0 + 2];
        #pragma unroll
        for (int nt = 0; nt < 4; ++nt)
            o[nt] = __builtin_amdgcn_mfma_f32_16x16x32_bf16(pu.v, vb[k0][nt], o[nt], 0, 0, 0);
    }
}

__global__ void __launch_bounds__(256) attn_kernel(
    const unsigned short* __restrict__ Q, const unsigned short* __restrict__ K,
    const unsigned short* __restrict__ Vt, unsigned short* __restrict__ Rt2)
{
    __shared__ __align__(16) char sbuf[2][16384];   // [dbuf][K 8KB | V 8KB]

    const int bx   = blockIdx.x;                // 0..399
    const int b    = 2 * (bx & 7) + (((bx >> 3) >= 25) ? 1 : 0);
    const int qt   = (bx >> 3) % 25;            // 64-query tile
    const int tid  = threadIdx.x;
    const int wv_  = tid >> 6;
    const int lane = tid & 63;
    const int l16  = lane & 15, quad = lane >> 4;

    const unsigned short* Qg = Q  + ((size_t)b * NTOK + qt * 64 + wv_ * 16) * HCH;
    const unsigned short* Kg = K  + (size_t)b * NTOK * HCH;
    const unsigned short* Vg = Vt + (size_t)b * HCH * NTOK;

    // staging source geometry (per lane): row-in-chunk, inverse-swizzled col
    const int srow  = lane >> 3;                        // 0..7
    const int scole = 8 * ((lane & 7) ^ srow);          // source col (elems)

    // Q fragments (B-operand of the swapped QK^T), resident all kernel
    bf16x8 qa[2];
    #pragma unroll
    for (int k0 = 0; k0 < 2; ++k0)
        qa[k0] = *((const bf16x8*)(Qg + (size_t)l16 * HCH + k0 * 32 + quad * 8));

    f32x4 o[4];
    float rs = 0.f;
    #pragma unroll
    for (int nt = 0; nt < 4; ++nt)
        #pragma unroll
        for (int r = 0; r < 4; ++r) o[nt][r] = 0.f;

    // ---- counted-vmcnt double-buffered k-loop over all 25 tiles ----
    attn_stage_tile(Kg, Vg, sbuf[0], 0, wv_, srow, scole);
    int cur = 0;
    for (int kt = 0; kt < 25; ++kt) {
        if (kt + 1 < 25) {
            attn_stage_tile(Kg, Vg, sbuf[cur ^ 1], kt + 1, wv_, srow, scole);
            asm volatile("s_waitcnt vmcnt(4)" ::: "memory");
        } else {
            asm volatile("s_waitcnt vmcnt(0)" ::: "memory");
        }
        __builtin_amdgcn_sched_barrier(0);
        __builtin_amdgcn_s_barrier();
        __builtin_amdgcn_sched_barrier(0);
        attn_compute_lds(sbuf[cur], sbuf[cur] + 8192, l16, quad, qa, o, rs);
        __builtin_amdgcn_sched_barrier(0);
        __builtin_amdgcn_s_barrier();
        cur ^= 1;
    }

    // ---- complete row sums (q = l16) across the 4 quads ----
    rs += __shfl_xor(rs, 16);
    rs += __shfl_xor(rs, 32);
    // redistribute to o's q layout (q = quad*4 + r): source lanes 0..15
    float rsq[4];
    #pragma unroll
    for (int r = 0; r < 4; ++r) rsq[r] = __shfl(rs, quad * 4 + r);

    // ---- direct output: Rt2[b][t=qt][h=nt*16+l16][j=wv_*16+quad*4+r] ----
    unsigned short* Rg = Rt2 + ((size_t)(b * 25 + qt)) * HCH * HCH;
    #pragma unroll
    for (int nt = 0; nt < 4; ++nt) {
        ushort4 pk;
        pk.x = f2bf(o[nt][0] / rsq[0]);
        pk.y = f2bf(o[nt][1] / rsq[1]);
        pk.z = f2bf(o[nt][2] / rsq[2]);
        pk.w = f2bf(o[nt][3] / rsq[3]);
        *((ushort4*)(Rg + (size_t)(nt * 16 + l16) * HCH + wv_ * 16 + quad * 4)) = pk;
    }
}

// ---------------------------------------------------------------------------
// Output projection: out[b][c][h*25+t] = sum_j wo[j][c] * Rt2[b][t][h][j]
// Grid (16 b, 8 c-tiles, 25 n-tiles): one 64x64 output tile per block.
// ---------------------------------------------------------------------------
__global__ void __launch_bounds__(256) outproj_kernel(
    const unsigned short* __restrict__ Rt2, const unsigned short* __restrict__ WoT,
    float* __restrict__ out)
{
    __shared__ __align__(16) unsigned short Aw[64 * LDA];

    const int b    = blockIdx.x;
    const int ct   = blockIdx.y;
    const int nt64 = blockIdx.z;
    const int tid  = threadIdx.x;
    const int wv_  = tid >> 6;
    const int lane = tid & 63;
    const int l16  = lane & 15, quad = lane >> 4;

    #pragma unroll
    for (int r = 0; r < 2; ++r) {
        const int task = tid + r * 256;
        const int row = task >> 3, ch = task & 7;
        *((int4*)(Aw + row * LDA + ch * 8)) =
            *((const int4*)(WoT + ((size_t)(ct * 64 + row)) * HCH + ch * 8));
    }
    __syncthreads();

    const int n = nt64 * 64 + wv_ * 16 + l16;
    const int h = n / 25, t = n % 25;
    const unsigned short* bsrc = Rt2 + ((size_t)(b * 25 + t) * HCH + h) * HCH;

    f32x4 acc[4];
    #pragma unroll
    for (int mt = 0; mt < 4; ++mt)
        #pragma unroll
        for (int r = 0; r < 4; ++r) acc[mt][r] = 0.f;

    #pragma unroll
    for (int k0 = 0; k0 < 2; ++k0) {
        const bf16x8 bv = *((const bf16x8*)(bsrc + k0 * 32 + quad * 8));
        #pragma unroll
        for (int mt = 0; mt < 4; ++mt) {
            const bf16x8 av = *((const bf16x8*)(Aw + (mt * 16 + l16) * LDA + k0 * 32 + quad * 8));
            acc[mt] = __builtin_amdgcn_mfma_f32_16x16x32_bf16(av, bv, acc[mt], 0, 0, 0);
        }
    }
    #pragma unroll
    for (int mt = 0; mt < 4; ++mt)
        #pragma unroll
        for (int r = 0; r < 4; ++r)
            out[((size_t)b * CIN + ct * 64 + mt * 16 + quad * 4 + r) * NTOK + n] = acc[mt][r];
}

// ---------------------------------------------------------------------------
extern "C" void kernel_launch(void* const* d_in, const int* in_sizes, int n_in,
                              void* d_out, int out_size, void* d_ws, size_t ws_size,
                              hipStream_t stream)
{
    const float* rgb = (const float*)d_in[0];
    const float* hsi = (const float*)d_in[1];
    const float* wq  = (const float*)d_in[2];
    const float* wk  = (const float*)d_in[3];
    const float* wv  = (const float*)d_in[4];
    const float* wo  = (const float*)d_in[5];
    float* out = (float*)d_out;

    unsigned short* Wt  = (unsigned short*)d_ws;
    unsigned short* WoT = Wt  + (size_t)3 * HCH * CIN;
    unsigned short* Qb  = WoT + (size_t)CIN * HCH;
    unsigned short* Kb  = Qb  + (size_t)NB * NTOK * HCH;
    unsigned short* Vtb = Kb  + (size_t)NB * NTOK * HCH;
    unsigned short* Rt2 = Vtb + (size_t)NB * NTOK * HCH;

    wprep_kernel<<<dim3(64), 256, 0, stream>>>(wq, wk, wv, wo, Wt, WoT);
    proj_kernel<<<dim3(NB * 25, 2), 256, 0, stream>>>(rgb, hsi, Wt, Qb, Kb, Vtb);
    attn_kernel<<<dim3(NB * 25), 256, 0, stream>>>(Qb, Kb, Vtb, Rt2);
    outproj_kernel<<<dim3(NB, 8, 25), 256, 0, stream>>>(Rt2, WoT, out);
}